// Round 25
// baseline (439.539 us; speedup 1.0000x reference)
//
#include <hip/hip_runtime.h>

#define NN 100000
#define IN_F 128
#define OUT_F 64
#define PP 3
#define EE 1600000
#define TOT (PP * EE)                // 4.8M edges
#define HID 32
#define SEG_N (PP * NN)              // 300000
#define NC1024 98                    // coarse blocks of 1024 nodes
#define NCB (NC1024 * PP)            // 294 coarse bins
#define CAPC 19456                   // coarse dst-bin capacity (padded runs; mult of 16)
#define CAPS 21504                   // coarse src-bin capacity u16 (mult of 32)
#define CHUNK 8192                   // edges per scatter block
#define NSX ((EE + CHUNK - 1) / CHUNK)      // 196 scatter blocks per metapath
#define NFB (NCB * 32)               // 9408 fine gather bins (32 nodes each)
#define WSLOTS 256

__device__ __forceinline__ unsigned short f2bf(float f) {
    unsigned u = __float_as_uint(f);
    u += 0x7FFFu + ((u >> 16) & 1u);           // round to nearest even
    return (unsigned short)(u >> 16);
}
__device__ __forceinline__ float bf2f(unsigned short b) {
    return __uint_as_float((unsigned)b << 16);
}
__device__ __forceinline__ float tanh_fast(float x) {
    float ax = fabsf(x);
    float e = __expf(-2.f * ax);
    float t = (1.f - e) / (1.f + e);
    return copysignf(t, x);
}

// ---------------------------------------------------------------- dst-key multisplit with block-local
// counting sort: histogram -> prefix -> LDS permute -> dense coalesced per-bin burst writes.
__global__ void scatter_sortd(const int* __restrict__ src, const int* __restrict__ dst,
                              unsigned* __restrict__ gcur_d, unsigned* __restrict__ gbuf_d) {
    __shared__ unsigned sorted[CHUNK];          // 32 KB
    __shared__ unsigned hist4[4][NC1024];
    __shared__ unsigned pre[NC1024 + 1];
    __shared__ unsigned wcur[4][NC1024];
    __shared__ unsigned gbase[NC1024];
    int tid = threadIdx.x, wv = tid >> 6;
    int p = blockIdx.y;
    for (int i = tid; i < 4 * NC1024; i += 256) hist4[i / NC1024][i % NC1024] = 0u;
    __syncthreads();
    int e0 = blockIdx.x * CHUNK;
    const int* sp = src + (size_t)p * EE;
    const int* dp = dst + (size_t)p * EE;
    for (int i = 0; i < CHUNK / 256; ++i) {
        int e = e0 + i * 256 + tid;
        if (e < EE) atomicAdd(&hist4[wv][dp[e] >> 10], 1u);
    }
    __syncthreads();
    if (tid == 0) {
        unsigned a = 0;
        for (int b = 0; b < NC1024; ++b) {
            pre[b] = a;
            a += hist4[0][b] + hist4[1][b] + hist4[2][b] + hist4[3][b];
        }
        pre[NC1024] = a;
    }
    __syncthreads();
    if (tid < NC1024) {
        unsigned a = pre[tid];
        wcur[0][tid] = a; a += hist4[0][tid];
        wcur[1][tid] = a; a += hist4[1][tid];
        wcur[2][tid] = a; a += hist4[2][tid];
        wcur[3][tid] = a; a += hist4[3][tid];
        unsigned tt = a - pre[tid];
        gbase[tid] = tt ? atomicAdd(&gcur_d[tid * PP + p], (tt + 15u) & ~15u) : 0u;
    }
    __syncthreads();
    for (int i = 0; i < CHUNK / 256; ++i) {
        int e = e0 + i * 256 + tid;
        if (e < EE) {
            int s = sp[e], d = dp[e];
            unsigned pos = atomicAdd(&wcur[wv][(unsigned)d >> 10], 1u);
            sorted[pos] = (unsigned)s | ((unsigned)(d & 1023) << 17);
        }
    }
    __syncthreads();
    for (int b = 0; b < NC1024; ++b) {
        unsigned st = pre[b], len = pre[b + 1] - st;
        if (!len) continue;
        unsigned padded = (len + 15u) & ~15u;
        unsigned gb = gbase[b];
        size_t gout = (size_t)(b * PP + p) * CAPC;
        for (unsigned j = tid; j < padded; j += 256)
            if (gb + j < CAPC)
                gbuf_d[gout + gb + j] = (j < len) ? sorted[st + j] : 0xFFFFFFFFu;
    }
}

// ---------------------------------------------------------------- src-key multisplit, same structure (u16)
__global__ void scatter_sorts(const int* __restrict__ src,
                              unsigned* __restrict__ gcur_s, unsigned short* __restrict__ gbuf_s) {
    __shared__ unsigned short sorted[CHUNK];    // 16 KB
    __shared__ unsigned hist4[4][NC1024];
    __shared__ unsigned pre[NC1024 + 1];
    __shared__ unsigned wcur[4][NC1024];
    __shared__ unsigned gbase[NC1024];
    int tid = threadIdx.x, wv = tid >> 6;
    int p = blockIdx.y;
    for (int i = tid; i < 4 * NC1024; i += 256) hist4[i / NC1024][i % NC1024] = 0u;
    __syncthreads();
    int e0 = blockIdx.x * CHUNK;
    const int* sp = src + (size_t)p * EE;
    for (int i = 0; i < CHUNK / 256; ++i) {
        int e = e0 + i * 256 + tid;
        if (e < EE) atomicAdd(&hist4[wv][sp[e] >> 10], 1u);
    }
    __syncthreads();
    if (tid == 0) {
        unsigned a = 0;
        for (int b = 0; b < NC1024; ++b) {
            pre[b] = a;
            a += hist4[0][b] + hist4[1][b] + hist4[2][b] + hist4[3][b];
        }
        pre[NC1024] = a;
    }
    __syncthreads();
    if (tid < NC1024) {
        unsigned a = pre[tid];
        wcur[0][tid] = a; a += hist4[0][tid];
        wcur[1][tid] = a; a += hist4[1][tid];
        wcur[2][tid] = a; a += hist4[2][tid];
        wcur[3][tid] = a; a += hist4[3][tid];
        unsigned tt = a - pre[tid];
        gbase[tid] = tt ? atomicAdd(&gcur_s[tid * PP + p], (tt + 31u) & ~31u) : 0u;
    }
    __syncthreads();
    for (int i = 0; i < CHUNK / 256; ++i) {
        int e = e0 + i * 256 + tid;
        if (e < EE) {
            int s = sp[e];
            unsigned pos = atomicAdd(&wcur[wv][(unsigned)s >> 10], 1u);
            sorted[pos] = (unsigned short)(s & 1023);
        }
    }
    __syncthreads();
    for (int b = 0; b < NC1024; ++b) {
        unsigned st = pre[b], len = pre[b + 1] - st;
        if (!len) continue;
        unsigned padded = (len + 31u) & ~31u;
        unsigned gb = gbase[b];
        size_t gout = (size_t)(b * PP + p) * CAPS;
        for (unsigned j = tid; j < padded; j += 256)
            if (gb + j < CAPS)
                gbuf_s[gout + gb + j] = (j < len) ? sorted[st + j] : (unsigned short)0xFFFFu;
    }
}

// ---------------------------------------------------------------- per-coarse-src-bin LDS histogram -> nsrc (f32)
__global__ void src_hist(const unsigned* __restrict__ gcur_s, const unsigned short* __restrict__ gbuf_s,
                         float* __restrict__ nsrc) {
    __shared__ unsigned hist[4][1024];   // 16 KB
    int tid = threadIdx.x;
    int wv = tid >> 6;
    for (int i = tid; i < 4 * 1024; i += 256) hist[i >> 10][i & 1023] = 0u;
    __syncthreads();
    int c = blockIdx.x;
    int blk = c / PP, p = c - blk * PP;
    unsigned cnt = gcur_s[c]; if (cnt > CAPS) cnt = CAPS;
    const unsigned short* gb = gbuf_s + (size_t)c * CAPS;
    for (unsigned j = tid; j < cnt; j += 256) {
        unsigned v = gb[j];
        if (v <= 1023u) atomicAdd(&hist[wv][v], 1u);   // skip sentinels
    }
    __syncthreads();
    for (int i = tid; i < 1024; i += 256) {
        int n = blk * 1024 + i;
        unsigned hv = hist[0][i] + hist[1][i] + hist[2][i] + hist[3][i];
        if (n < NN) nsrc[p * NN + n] = rsqrtf(fmaxf((float)hv, 1.f));
    }
}

// ---------------------------------------------------------------- proj_fused: projp_p = (h @ gc_w) * nsrc_p, bf16
__global__ void __launch_bounds__(256) proj_fused(const float* __restrict__ h,
                                                  const float* __restrict__ gc_w,
                                                  const float* __restrict__ nsrc,
                                                  unsigned short* __restrict__ t0,
                                                  unsigned short* __restrict__ t1,
                                                  unsigned short* __restrict__ t2) {
    __shared__ float w_lds[IN_F * OUT_F];   // 32 KB
    __shared__ float h_lds[32 * IN_F];      // 16 KB
    int tid = threadIdx.x;
    for (int i = tid; i < IN_F * OUT_F / 4; i += 256)
        ((float4*)w_lds)[i] = ((const float4*)gc_w)[i];
    size_t r0 = (size_t)blockIdx.x * 32;
    for (int i = tid; i < 32 * IN_F / 4; i += 256)
        ((float4*)h_lds)[i] = ((const float4*)(h + r0 * IN_F))[i];
    __syncthreads();
    int wave = tid >> 6, lane = tid & 63;
    float acc[8] = {0.f, 0.f, 0.f, 0.f, 0.f, 0.f, 0.f, 0.f};
    for (int k = 0; k < IN_F; k += 4) {
        float w0 = w_lds[k * OUT_F + lane];
        float w1 = w_lds[(k + 1) * OUT_F + lane];
        float w2 = w_lds[(k + 2) * OUT_F + lane];
        float w3 = w_lds[(k + 3) * OUT_F + lane];
#pragma unroll
        for (int r = 0; r < 8; ++r) {
            float4 hv = *(const float4*)&h_lds[(wave * 8 + r) * IN_F + k];
            acc[r] = fmaf(hv.x, w0, fmaf(hv.y, w1, fmaf(hv.z, w2, fmaf(hv.w, w3, acc[r]))));
        }
    }
#pragma unroll
    for (int r = 0; r < 8; ++r) {
        size_t n = r0 + wave * 8 + r;
        float a = acc[r];
        t0[n * OUT_F + lane] = f2bf(a * nsrc[n]);
        t1[n * OUT_F + lane] = f2bf(a * nsrc[NN + n]);
        t2[n * OUT_F + lane] = f2bf(a * nsrc[2 * NN + n]);
    }
}

// ---------------------------------------------------------------- fine split IN PLACE, FULL NODE SORT:
// 1024-way counting sort per coarse bin -> contiguous per-node edge runs, payload = byte offset s<<7.
// foff/fcnt become per-node tables [c*1024 + (d&1023)]. Kills gather's LDS list-build entirely.
__global__ void fine_split(const unsigned* __restrict__ gcur_d, unsigned* __restrict__ gbuf_d,
                           unsigned* __restrict__ foff, unsigned* __restrict__ fcnt) {
    __shared__ unsigned stage[CAPC];      // 76 KB
    __shared__ unsigned hist[4][1024];    // 16 KB
    __shared__ unsigned cur[4][1024];     // 16 KB
    __shared__ unsigned scan[256];        // 1 KB   (~110 KB total, 1 block/CU; 294 blocks ~ 1.15/CU)
    int c = blockIdx.x;
    int tid = threadIdx.x;
    int wv = tid >> 6;
    for (int i = tid; i < 4 * 1024; i += 256) hist[i >> 10][i & 1023] = 0u;
    __syncthreads();
    unsigned cnt = gcur_d[c]; if (cnt > CAPC) cnt = CAPC;
    unsigned* gb = gbuf_d + (size_t)c * CAPC;
    for (unsigned j = tid; j < cnt; j += 256) {
        unsigned v = gb[j];
        stage[j] = v;
        if (v != 0xFFFFFFFFu) atomicAdd(&hist[wv][(v >> 17) & 1023u], 1u);
    }
    __syncthreads();
    // block exclusive scan over 1024 bins: thread t owns bins 4t..4t+3
    unsigned t0h = hist[0][4 * tid]     + hist[1][4 * tid]     + hist[2][4 * tid]     + hist[3][4 * tid];
    unsigned t1h = hist[0][4 * tid + 1] + hist[1][4 * tid + 1] + hist[2][4 * tid + 1] + hist[3][4 * tid + 1];
    unsigned t2h = hist[0][4 * tid + 2] + hist[1][4 * tid + 2] + hist[2][4 * tid + 2] + hist[3][4 * tid + 2];
    unsigned t3h = hist[0][4 * tid + 3] + hist[1][4 * tid + 3] + hist[2][4 * tid + 3] + hist[3][4 * tid + 3];
    unsigned tsum = t0h + t1h + t2h + t3h;
    unsigned x = tsum;
    scan[tid] = x;
    __syncthreads();
    for (int off = 1; off < 256; off <<= 1) {
        unsigned y = (tid >= off) ? scan[tid - off] : 0u;
        __syncthreads();
        x += y;
        scan[tid] = x;
        __syncthreads();
    }
    unsigned a = x - tsum;                 // exclusive prefix at bin 4*tid
    unsigned gbase = (unsigned)c * CAPC;
#pragma unroll
    for (int q = 0; q < 4; ++q) {
        int b = 4 * tid + q;
        unsigned h0 = hist[0][b], h1 = hist[1][b], h2 = hist[2][b], h3 = hist[3][b];
        foff[(size_t)c * 1024 + b] = gbase + a;
        fcnt[(size_t)c * 1024 + b] = h0 + h1 + h2 + h3;
        cur[0][b] = a; a += h0;
        cur[1][b] = a; a += h1;
        cur[2][b] = a; a += h2;
        cur[3][b] = a; a += h3;
    }
    __syncthreads();
    for (unsigned j = tid; j < cnt; j += 256) {
        unsigned v = stage[j];
        if (v == 0xFFFFFFFFu) continue;
        unsigned pos = atomicAdd(&cur[wv][(v >> 17) & 1023u], 1u);
        gb[pos] = (v & 0x1FFFFu) << 7;     // pure byte offset into bf16 table
    }
}

// ---------------------------------------------------------------- fine gather: NO list-build — per-node
// contiguous runs; lanes load edge offsets with one coalesced global read, then readlane loop.
__global__ void __launch_bounds__(256, 8)
gather3f(const unsigned* __restrict__ foff, const unsigned* __restrict__ fcnt,
         const unsigned* __restrict__ gbuf_f,
         const unsigned short* __restrict__ t0, const unsigned short* __restrict__ t1,
         const unsigned short* __restrict__ t2,
         const float* __restrict__ gc_b, const float* __restrict__ sa_w1,
         const float* __restrict__ sa_b1, const float* __restrict__ sa_w2,
         float* __restrict__ zbuf, float* __restrict__ wsum) {
    __shared__ unsigned nfo[32], nfc[32];   // per-node run meta
    __shared__ float zsh[4][OUT_F];
    int tid = threadIdx.x;
    int lane = tid & 63, wave = tid >> 6;
    int j = lane & 31, half = lane >> 5;
    unsigned w1p[16];                       // packed bf16 pairs of sa_w1
#pragma unroll
    for (int q = 0; q < 16; ++q) {
        float a = sa_w1[(half * 32 + 2 * q) * HID + j];
        float b = sa_w1[(half * 32 + 2 * q + 1) * HID + j];
        w1p[q] = (unsigned)f2bf(a) | ((unsigned)f2bf(b) << 16);
    }
    float b1r = sa_b1[j];
    float w2r = sa_w2[j];
    float bsr = gc_b[lane];

    int f = blockIdx.x;                  // fine bin: c*32 + sub
    int c = f >> 5, sub = f & 31;
    int blk = c / PP, p = c - blk * PP;
    const char* tpc = (const char*)((p == 0) ? t0 : (p == 1) ? t1 : t2);
    unsigned l2 = (unsigned)(lane << 1);
    if (tid < 32) {
        size_t g = (size_t)c * 1024 + sub * 32 + tid;
        nfo[tid] = foff[g];
        nfc[tid] = fcnt[g];
    }
    __syncthreads();

    int nbase = blk * 1024 + sub * 32;
    float logacc = 0.f;
    for (int k = 0; k < 8; ++k) {            // 8 nodes per wave
        int node = wave * 8 + k;
        int n = nbase + node;
        if (n >= NN) continue;
        unsigned ind = nfc[node];
        unsigned c2 = ind < 64u ? ind : 64u;
        unsigned pl = gbuf_f[nfo[node] + lane];   // coalesced per-node run read (garbage if lane>=c2)
        float acc = 0.f;
        unsigned i = 0;
        for (; i + 8 <= c2; i += 8) {        // 8 independent loads in flight
            unsigned o0 = (unsigned)__builtin_amdgcn_readlane((int)pl, (int)i);
            unsigned o1 = (unsigned)__builtin_amdgcn_readlane((int)pl, (int)i + 1);
            unsigned o2 = (unsigned)__builtin_amdgcn_readlane((int)pl, (int)i + 2);
            unsigned o3 = (unsigned)__builtin_amdgcn_readlane((int)pl, (int)i + 3);
            unsigned o4 = (unsigned)__builtin_amdgcn_readlane((int)pl, (int)i + 4);
            unsigned o5 = (unsigned)__builtin_amdgcn_readlane((int)pl, (int)i + 5);
            unsigned o6 = (unsigned)__builtin_amdgcn_readlane((int)pl, (int)i + 6);
            unsigned o7 = (unsigned)__builtin_amdgcn_readlane((int)pl, (int)i + 7);
            float p0 = bf2f(*(const unsigned short*)(tpc + (o0 + l2)));
            float p1 = bf2f(*(const unsigned short*)(tpc + (o1 + l2)));
            float p2 = bf2f(*(const unsigned short*)(tpc + (o2 + l2)));
            float p3 = bf2f(*(const unsigned short*)(tpc + (o3 + l2)));
            float p4 = bf2f(*(const unsigned short*)(tpc + (o4 + l2)));
            float p5 = bf2f(*(const unsigned short*)(tpc + (o5 + l2)));
            float p6 = bf2f(*(const unsigned short*)(tpc + (o6 + l2)));
            float p7 = bf2f(*(const unsigned short*)(tpc + (o7 + l2)));
            acc += ((p0 + p1) + (p2 + p3)) + ((p4 + p5) + (p6 + p7));
        }
        for (; i < c2; ++i) {
            unsigned o0 = (unsigned)__builtin_amdgcn_readlane((int)pl, (int)i);
            acc += bf2f(*(const unsigned short*)(tpc + (o0 + l2)));
        }
        float ndv = rsqrtf(fmaxf((float)ind, 1.f));
        float zv = fmaxf(fmaf(acc, ndv, bsr), 0.f);
        zbuf[((size_t)n * PP + p) * OUT_F + lane] = zv;
        zsh[wave][lane] = zv;
        float hp = 0.f;
        const float4* zrow = (const float4*)&zsh[wave][half * 32];
#pragma unroll
        for (int q = 0; q < 8; ++q) {
            float4 zq = zrow[q];
            unsigned u0 = w1p[2 * q], u1 = w1p[2 * q + 1];
            hp = fmaf(zq.x, __uint_as_float(u0 << 16), hp);
            hp = fmaf(zq.y, __uint_as_float(u0 & 0xFFFF0000u), hp);
            hp = fmaf(zq.z, __uint_as_float(u1 << 16), hp);
            hp = fmaf(zq.w, __uint_as_float(u1 & 0xFFFF0000u), hp);
        }
        hp += __shfl_xor(hp, 32);
        logacc += tanh_fast(hp + b1r) * w2r;       // lane-sum over wave = 2x logit
    }
#pragma unroll
    for (int off = 1; off < 64; off <<= 1) logacc += __shfl_xor(logacc, off);
    if (lane == 0) atomicAdd(&wsum[(blockIdx.x & (WSLOTS - 1)) * PP + p], logacc * 0.5f);
}

// ---------------------------------------------------------------- beta = softmax(mean logits)
__global__ void beta_kernel(const float* __restrict__ wsum, float* __restrict__ beta) {
    if (threadIdx.x == 0) {
        float m[PP] = {0.f, 0.f, 0.f};
        for (int i = 0; i < WSLOTS; ++i)
            for (int p = 0; p < PP; ++p) m[p] += wsum[i * PP + p];
        float mx = -1e30f;
        for (int p = 0; p < PP; ++p) { m[p] *= (1.0f / NN); mx = fmaxf(mx, m[p]); }
        float e[PP], s = 0.f;
        for (int p = 0; p < PP; ++p) { e[p] = expf(m[p] - mx); s += e[p]; }
        for (int p = 0; p < PP; ++p) beta[p] = e[p] / s;
    }
}

// ---------------------------------------------------------------- out = sum_p beta[p] * z[:,p,:]
__global__ void out_kernel(const float* __restrict__ zbuf, const float* __restrict__ beta,
                           float* __restrict__ out) {
    int t = blockIdx.x * 256 + threadIdx.x;
    if (t >= NN * (OUT_F / 4)) return;
    int n = t >> 4;
    int q = t & 15;
    float b0 = beta[0], b1 = beta[1], b2 = beta[2];
    const float4 v0 = ((const float4*)(zbuf + ((size_t)n * PP + 0) * OUT_F))[q];
    const float4 v1 = ((const float4*)(zbuf + ((size_t)n * PP + 1) * OUT_F))[q];
    const float4 v2 = ((const float4*)(zbuf + ((size_t)n * PP + 2) * OUT_F))[q];
    float4 r;
    r.x = b0 * v0.x + b1 * v1.x + b2 * v2.x;
    r.y = b0 * v0.y + b1 * v1.y + b2 * v2.y;
    r.z = b0 * v0.z + b1 * v1.z + b2 * v2.z;
    r.w = b0 * v0.w + b1 * v1.w + b2 * v2.w;
    ((float4*)out)[t] = r;
}

extern "C" void kernel_launch(void* const* d_in, const int* in_sizes, int n_in,
                              void* d_out, int out_size, void* d_ws, size_t ws_size,
                              hipStream_t stream) {
    const float* h     = (const float*)d_in[0];
    const float* gc_w  = (const float*)d_in[1];
    const float* gc_b  = (const float*)d_in[2];
    const float* sa_w1 = (const float*)d_in[3];
    const float* sa_b1 = (const float*)d_in[4];
    const float* sa_w2 = (const float*)d_in[5];
    const int* esrc    = (const int*)d_in[6];
    const int* edst    = (const int*)d_in[7];

    float* out  = (float*)d_out;
    float* zbuf = out + (size_t)NN * OUT_F;              // z region of d_out: [N][P][64]
    unsigned short* t0 = (unsigned short*)out;           // projp0: out[0:12.8M)
    unsigned short* t1 = t0 + (size_t)NN * OUT_F;        // projp1: out[12.8:25.6M)

    char* ws = (char*)d_ws;                              // peak ws use ~39.7 MB (41.4 MB proven)
    const size_t OFF_GBD  = 0;                           // gbuf_d: 294*19456*4 = 22,880,256
    const size_t OFF_GBS  = 22900000;                    // gbuf_s u16 (freed after src_hist)
    const size_t OFF_T2   = 22900000;                    // projp2 (12.8M) — overlays gbuf_s after src_hist
    const size_t OFF_NSRC = 35800000;                    // nsrc f32 [3][NN]: 1.2 MB
    const size_t OFF_FOFF = 37100000;                    // per-node offsets: 294*1024*4 = 1,204,224
    const size_t OFF_FCNT = 38350000;                    // per-node counts:  1,204,224
    const size_t OFF_GCD  = 39600000;
    const size_t OFF_GCS  = 39610000;
    const size_t OFF_WSUM = 39620000;
    const size_t OFF_BETA = 39630000;

    unsigned* gbuf_d       = (unsigned*)(ws + OFF_GBD);
    unsigned short* gbuf_s = (unsigned short*)(ws + OFF_GBS);
    unsigned short* t2     = (unsigned short*)(ws + OFF_T2);
    float* nsrc            = (float*)(ws + OFF_NSRC);
    unsigned* foff         = (unsigned*)(ws + OFF_FOFF);
    unsigned* fcnt         = (unsigned*)(ws + OFF_FCNT);
    unsigned* gcur_d       = (unsigned*)(ws + OFF_GCD);
    unsigned* gcur_s       = (unsigned*)(ws + OFF_GCS);
    float* wsum            = (float*)(ws + OFF_WSUM);
    float* beta            = (float*)(ws + OFF_BETA);

    hipMemsetAsync(gcur_d, 0, NCB * sizeof(unsigned), stream);
    hipMemsetAsync(gcur_s, 0, NCB * sizeof(unsigned), stream);
    hipMemsetAsync(wsum, 0, WSLOTS * PP * sizeof(float), stream);

    scatter_sortd<<<dim3(NSX, PP), 256, 0, stream>>>(esrc, edst, gcur_d, gbuf_d);
    scatter_sorts<<<dim3(NSX, PP), 256, 0, stream>>>(esrc, gcur_s, gbuf_s);
    src_hist<<<NCB, 256, 0, stream>>>(gcur_s, gbuf_s, nsrc);              // consumes gbuf_s
    proj_fused<<<NN / 32, 256, 0, stream>>>(h, gc_w, nsrc, t0, t1, t2);   // t2 overlays freed gbuf_s
    fine_split<<<NCB, 256, 0, stream>>>(gcur_d, gbuf_d, foff, fcnt);      // 1024-way in-place sort
    gather3f<<<NFB, 256, 0, stream>>>(foff, fcnt, gbuf_d, t0, t1, t2,
                                      gc_b, sa_w1, sa_b1, sa_w2, zbuf, wsum);
    beta_kernel<<<1, 64, 0, stream>>>(wsum, beta);
    out_kernel<<<(NN * (OUT_F / 4) + 255) / 256, 256, 0, stream>>>(zbuf, beta, out);
}

// Round 26
// 415.034 us; speedup vs baseline: 1.0590x; 1.0590x over previous
//
#include <hip/hip_runtime.h>

#define NN 100000
#define IN_F 128
#define OUT_F 64
#define PP 3
#define EE 1600000
#define TOT (PP * EE)                // 4.8M edges
#define HID 32
#define SEG_N (PP * NN)              // 300000
#define NC1024 98                    // coarse blocks of 1024 nodes
#define NCB (NC1024 * PP)            // 294 coarse bins
#define CAPC 19456                   // coarse dst-bin capacity (padded runs; mult of 16)
#define CAPS 21504                   // coarse src-bin capacity u16 (mult of 32)
#define CHUNK 8192                   // edges per scatter block
#define NSX ((EE + CHUNK - 1) / CHUNK)      // 196 scatter blocks per metapath
#define LCAP 64                      // per-node edge list capacity
#define NFB (NCB * 32)               // 9408 fine bins
#define WSLOTS 256

__device__ __forceinline__ unsigned short f2bf(float f) {
    unsigned u = __float_as_uint(f);
    u += 0x7FFFu + ((u >> 16) & 1u);           // round to nearest even
    return (unsigned short)(u >> 16);
}
__device__ __forceinline__ float bf2f(unsigned short b) {
    return __uint_as_float((unsigned)b << 16);
}
__device__ __forceinline__ float tanh_fast(float x) {
    float ax = fabsf(x);
    float e = __expf(-2.f * ax);
    float t = (1.f - e) / (1.f + e);
    return copysignf(t, x);
}

// ---------------------------------------------------------------- dst-key multisplit with block-local
// counting sort: histogram -> prefix -> LDS permute -> dense coalesced per-bin burst writes.
__global__ void scatter_sortd(const int* __restrict__ src, const int* __restrict__ dst,
                              unsigned* __restrict__ gcur_d, unsigned* __restrict__ gbuf_d) {
    __shared__ unsigned sorted[CHUNK];          // 32 KB
    __shared__ unsigned hist4[4][NC1024];
    __shared__ unsigned pre[NC1024 + 1];
    __shared__ unsigned wcur[4][NC1024];
    __shared__ unsigned gbase[NC1024];
    int tid = threadIdx.x, wv = tid >> 6;
    int p = blockIdx.y;
    for (int i = tid; i < 4 * NC1024; i += 256) hist4[i / NC1024][i % NC1024] = 0u;
    __syncthreads();
    int e0 = blockIdx.x * CHUNK;
    const int* sp = src + (size_t)p * EE;
    const int* dp = dst + (size_t)p * EE;
    for (int i = 0; i < CHUNK / 256; ++i) {
        int e = e0 + i * 256 + tid;
        if (e < EE) atomicAdd(&hist4[wv][dp[e] >> 10], 1u);
    }
    __syncthreads();
    if (tid == 0) {
        unsigned a = 0;
        for (int b = 0; b < NC1024; ++b) {
            pre[b] = a;
            a += hist4[0][b] + hist4[1][b] + hist4[2][b] + hist4[3][b];
        }
        pre[NC1024] = a;
    }
    __syncthreads();
    if (tid < NC1024) {
        unsigned a = pre[tid];
        wcur[0][tid] = a; a += hist4[0][tid];
        wcur[1][tid] = a; a += hist4[1][tid];
        wcur[2][tid] = a; a += hist4[2][tid];
        wcur[3][tid] = a; a += hist4[3][tid];
        unsigned tt = a - pre[tid];
        gbase[tid] = tt ? atomicAdd(&gcur_d[tid * PP + p], (tt + 15u) & ~15u) : 0u;
    }
    __syncthreads();
    for (int i = 0; i < CHUNK / 256; ++i) {
        int e = e0 + i * 256 + tid;
        if (e < EE) {
            int s = sp[e], d = dp[e];
            unsigned pos = atomicAdd(&wcur[wv][(unsigned)d >> 10], 1u);
            sorted[pos] = (unsigned)s | ((unsigned)(d & 1023) << 17);
        }
    }
    __syncthreads();
    for (int b = 0; b < NC1024; ++b) {
        unsigned st = pre[b], len = pre[b + 1] - st;
        if (!len) continue;
        unsigned padded = (len + 15u) & ~15u;
        unsigned gb = gbase[b];
        size_t gout = (size_t)(b * PP + p) * CAPC;
        for (unsigned j = tid; j < padded; j += 256)
            if (gb + j < CAPC)
                gbuf_d[gout + gb + j] = (j < len) ? sorted[st + j] : 0xFFFFFFFFu;
    }
}

// ---------------------------------------------------------------- src-key multisplit, same structure (u16)
__global__ void scatter_sorts(const int* __restrict__ src,
                              unsigned* __restrict__ gcur_s, unsigned short* __restrict__ gbuf_s) {
    __shared__ unsigned short sorted[CHUNK];    // 16 KB
    __shared__ unsigned hist4[4][NC1024];
    __shared__ unsigned pre[NC1024 + 1];
    __shared__ unsigned wcur[4][NC1024];
    __shared__ unsigned gbase[NC1024];
    int tid = threadIdx.x, wv = tid >> 6;
    int p = blockIdx.y;
    for (int i = tid; i < 4 * NC1024; i += 256) hist4[i / NC1024][i % NC1024] = 0u;
    __syncthreads();
    int e0 = blockIdx.x * CHUNK;
    const int* sp = src + (size_t)p * EE;
    for (int i = 0; i < CHUNK / 256; ++i) {
        int e = e0 + i * 256 + tid;
        if (e < EE) atomicAdd(&hist4[wv][sp[e] >> 10], 1u);
    }
    __syncthreads();
    if (tid == 0) {
        unsigned a = 0;
        for (int b = 0; b < NC1024; ++b) {
            pre[b] = a;
            a += hist4[0][b] + hist4[1][b] + hist4[2][b] + hist4[3][b];
        }
        pre[NC1024] = a;
    }
    __syncthreads();
    if (tid < NC1024) {
        unsigned a = pre[tid];
        wcur[0][tid] = a; a += hist4[0][tid];
        wcur[1][tid] = a; a += hist4[1][tid];
        wcur[2][tid] = a; a += hist4[2][tid];
        wcur[3][tid] = a; a += hist4[3][tid];
        unsigned tt = a - pre[tid];
        gbase[tid] = tt ? atomicAdd(&gcur_s[tid * PP + p], (tt + 31u) & ~31u) : 0u;
    }
    __syncthreads();
    for (int i = 0; i < CHUNK / 256; ++i) {
        int e = e0 + i * 256 + tid;
        if (e < EE) {
            int s = sp[e];
            unsigned pos = atomicAdd(&wcur[wv][(unsigned)s >> 10], 1u);
            sorted[pos] = (unsigned short)(s & 1023);
        }
    }
    __syncthreads();
    for (int b = 0; b < NC1024; ++b) {
        unsigned st = pre[b], len = pre[b + 1] - st;
        if (!len) continue;
        unsigned padded = (len + 31u) & ~31u;
        unsigned gb = gbase[b];
        size_t gout = (size_t)(b * PP + p) * CAPS;
        for (unsigned j = tid; j < padded; j += 256)
            if (gb + j < CAPS)
                gbuf_s[gout + gb + j] = (j < len) ? sorted[st + j] : (unsigned short)0xFFFFu;
    }
}

// ---------------------------------------------------------------- per-coarse-src-bin LDS histogram -> deg8
__global__ void src_hist(const unsigned* __restrict__ gcur_s, const unsigned short* __restrict__ gbuf_s,
                         unsigned char* __restrict__ deg8) {
    __shared__ unsigned hist[4][1024];   // 16 KB
    int tid = threadIdx.x;
    int wv = tid >> 6;
    for (int i = tid; i < 4 * 1024; i += 256) hist[i >> 10][i & 1023] = 0u;
    __syncthreads();
    int c = blockIdx.x;
    int blk = c / PP, p = c - blk * PP;
    unsigned cnt = gcur_s[c]; if (cnt > CAPS) cnt = CAPS;
    const unsigned short* gb = gbuf_s + (size_t)c * CAPS;
    for (unsigned j = tid; j < cnt; j += 256) {
        unsigned v = gb[j];
        if (v <= 1023u) atomicAdd(&hist[wv][v], 1u);   // skip sentinels
    }
    __syncthreads();
    for (int i = tid; i < 1024; i += 256) {
        int n = blk * 1024 + i;
        unsigned hv = hist[0][i] + hist[1][i] + hist[2][i] + hist[3][i];
        if (n < NN) deg8[p * NN + n] = (unsigned char)(hv < 63u ? hv : 63u);
    }
}

// ---------------------------------------------------------------- proj: single UNSCALED bf16 table
// (12.8MB; weight applied per edge via deg LUT) -> 3x less per-XCD L2 fill than 3 prescaled tables.
__global__ void __launch_bounds__(256) proj_kernel(const float* __restrict__ h,
                                                   const float* __restrict__ gc_w,
                                                   unsigned short* __restrict__ t) {
    __shared__ float w_lds[IN_F * OUT_F];   // 32 KB
    __shared__ float h_lds[32 * IN_F];      // 16 KB
    int tid = threadIdx.x;
    for (int i = tid; i < IN_F * OUT_F / 4; i += 256)
        ((float4*)w_lds)[i] = ((const float4*)gc_w)[i];
    size_t r0 = (size_t)blockIdx.x * 32;
    for (int i = tid; i < 32 * IN_F / 4; i += 256)
        ((float4*)h_lds)[i] = ((const float4*)(h + r0 * IN_F))[i];
    __syncthreads();
    int wave = tid >> 6, lane = tid & 63;
    float acc[8] = {0.f, 0.f, 0.f, 0.f, 0.f, 0.f, 0.f, 0.f};
    for (int k = 0; k < IN_F; k += 4) {
        float w0 = w_lds[k * OUT_F + lane];
        float w1 = w_lds[(k + 1) * OUT_F + lane];
        float w2 = w_lds[(k + 2) * OUT_F + lane];
        float w3 = w_lds[(k + 3) * OUT_F + lane];
#pragma unroll
        for (int r = 0; r < 8; ++r) {
            float4 hv = *(const float4*)&h_lds[(wave * 8 + r) * IN_F + k];
            acc[r] = fmaf(hv.x, w0, fmaf(hv.y, w1, fmaf(hv.z, w2, fmaf(hv.w, w3, acc[r]))));
        }
    }
#pragma unroll
    for (int r = 0; r < 8; ++r)
        t[(r0 + wave * 8 + r) * OUT_F + lane] = f2bf(acc[r]);
}

// ---------------------------------------------------------------- fine split IN PLACE (sentinel-aware)
// Output payload: (s<<7) | node | (deg6<<25) — byte offset, node low 5 bits, src degree bits 25-30.
__global__ void fine_split(const unsigned* __restrict__ gcur_d, unsigned* __restrict__ gbuf_d,
                           const unsigned char* __restrict__ deg8,
                           unsigned* __restrict__ foff, unsigned* __restrict__ fcnt) {
    __shared__ unsigned stage[CAPC];     // 76 KB
    __shared__ unsigned hist[4][32], pre[32], cur[4][32];
    int c = blockIdx.x;
    int tid = threadIdx.x;
    int wv = tid >> 6;
    if (tid < 32) { hist[0][tid] = 0u; hist[1][tid] = 0u; hist[2][tid] = 0u; hist[3][tid] = 0u; }
    __syncthreads();
    int blkc = c / PP, p = c - blkc * PP;
    (void)blkc;
    unsigned cnt = gcur_d[c]; if (cnt > CAPC) cnt = CAPC;
    unsigned* gb = gbuf_d + (size_t)c * CAPC;
    for (unsigned j = tid; j < cnt; j += 256) {
        unsigned v = gb[j];
        stage[j] = v;
        if (v != 0xFFFFFFFFu) atomicAdd(&hist[wv][v >> 22], 1u);   // sub = (d&1023)>>5
    }
    __syncthreads();
    if (tid == 0) {
        unsigned a = 0;
        for (int i = 0; i < 32; ++i) {
            pre[i] = a;
            a += hist[0][i] + hist[1][i] + hist[2][i] + hist[3][i];
        }
    }
    __syncthreads();
    if (tid < 32) {
        unsigned a = pre[tid];
        cur[0][tid] = a; a += hist[0][tid];
        cur[1][tid] = a; a += hist[1][tid];
        cur[2][tid] = a; a += hist[2][tid];
        cur[3][tid] = a; a += hist[3][tid];
        foff[c * 32 + tid] = (unsigned)c * CAPC + pre[tid];
        fcnt[c * 32 + tid] = a - pre[tid];
    }
    __syncthreads();
    for (unsigned j = tid; j < cnt; j += 256) {
        unsigned v = stage[j];
        if (v == 0xFFFFFFFFu) continue;
        unsigned pos = atomicAdd(&cur[wv][v >> 22], 1u);
        unsigned s = v & 0x1FFFFu;
        unsigned dg = deg8[p * NN + s];
        gb[pos] = (s << 7) | ((v >> 17) & 31u) | (dg << 25);   // byte-offset | node | deg
    }
}

// ---------------------------------------------------------------- fine gather: single table, per-edge
// weight from deg LUT (wave-uniform LDS broadcast after readlane).
__global__ void __launch_bounds__(256, 8)
gather3d(const unsigned* __restrict__ foff, const unsigned* __restrict__ fcnt,
         const unsigned* __restrict__ gbuf_f, const unsigned short* __restrict__ t,
         const float* __restrict__ gc_b, const float* __restrict__ sa_w1,
         const float* __restrict__ sa_b1, const float* __restrict__ sa_w2,
         float* __restrict__ zbuf, float* __restrict__ wsum) {
    __shared__ unsigned lists[32 * LCAP];   // 8 KB (offset | deg, node stripped)
    __shared__ unsigned lcnt[32];
    __shared__ float rsq_t[64];
    __shared__ float zsh[4][OUT_F];
    int tid = threadIdx.x;
    int lane = tid & 63, wave = tid >> 6;
    int j = lane & 31, half = lane >> 5;
    unsigned w1p[16];                       // packed bf16 pairs of sa_w1
#pragma unroll
    for (int q = 0; q < 16; ++q) {
        float a = sa_w1[(half * 32 + 2 * q) * HID + j];
        float b = sa_w1[(half * 32 + 2 * q + 1) * HID + j];
        w1p[q] = (unsigned)f2bf(a) | ((unsigned)f2bf(b) << 16);
    }
    float b1r = sa_b1[j];
    float w2r = sa_w2[j];
    float bsr = gc_b[lane];
    if (tid < 64) rsq_t[tid] = rsqrtf(fmaxf((float)tid, 1.f));
    if (tid < 32) lcnt[tid] = 0u;
    __syncthreads();

    int f = blockIdx.x;                  // fine bin: c*32 + sub
    int c = f >> 5, sub = f & 31;
    int blk = c / PP, p = c - blk * PP;
    const char* tpc = (const char*)t;
    unsigned l2 = (unsigned)(lane << 1);
    unsigned base = foff[f];
    unsigned cnt = fcnt[f];
    for (unsigned i = tid; i < cnt; i += 256) {
        unsigned v = gbuf_f[base + i];
        unsigned node = v & 31u;
        unsigned sl = atomicAdd(&lcnt[node], 1u);
        if (sl < LCAP) lists[node * LCAP + sl] = v & 0xFFFFFF80u;   // offset | deg (node cleared)
    }
    __syncthreads();

    int nbase = blk * 1024 + sub * 32;
    float logacc = 0.f;
    for (int k = 0; k < 8; ++k) {            // 8 nodes per wave
        int node = wave * 8 + k;
        int n = nbase + node;
        if (n >= NN) continue;
        unsigned ind = lcnt[node];
        unsigned c2 = ind < LCAP ? ind : LCAP;
        unsigned pl = lists[node * LCAP + lane];
        float acc = 0.f;
        unsigned i = 0;
        for (; i + 4 <= c2; i += 4) {
            unsigned o0 = (unsigned)__builtin_amdgcn_readlane((int)pl, (int)i);
            unsigned o1 = (unsigned)__builtin_amdgcn_readlane((int)pl, (int)i + 1);
            unsigned o2 = (unsigned)__builtin_amdgcn_readlane((int)pl, (int)i + 2);
            unsigned o3 = (unsigned)__builtin_amdgcn_readlane((int)pl, (int)i + 3);
            float w0 = rsq_t[o0 >> 25], w1w = rsq_t[o1 >> 25];
            float w2w = rsq_t[o2 >> 25], w3w = rsq_t[o3 >> 25];
            float p0 = bf2f(*(const unsigned short*)(tpc + ((o0 & 0x1FFFF80u) + l2)));
            float p1 = bf2f(*(const unsigned short*)(tpc + ((o1 & 0x1FFFF80u) + l2)));
            float p2 = bf2f(*(const unsigned short*)(tpc + ((o2 & 0x1FFFF80u) + l2)));
            float p3 = bf2f(*(const unsigned short*)(tpc + ((o3 & 0x1FFFF80u) + l2)));
            acc = fmaf(p0, w0, acc);
            acc = fmaf(p1, w1w, acc);
            acc = fmaf(p2, w2w, acc);
            acc = fmaf(p3, w3w, acc);
        }
        for (; i < c2; ++i) {
            unsigned o0 = (unsigned)__builtin_amdgcn_readlane((int)pl, (int)i);
            acc = fmaf(bf2f(*(const unsigned short*)(tpc + ((o0 & 0x1FFFF80u) + l2))), rsq_t[o0 >> 25], acc);
        }
        float ndv = rsqrtf(fmaxf((float)ind, 1.f));
        float zv = fmaxf(fmaf(acc, ndv, bsr), 0.f);
        zbuf[((size_t)n * PP + p) * OUT_F + lane] = zv;
        zsh[wave][lane] = zv;
        float hp = 0.f;
        const float4* zrow = (const float4*)&zsh[wave][half * 32];
#pragma unroll
        for (int q = 0; q < 8; ++q) {
            float4 zq = zrow[q];
            unsigned u0 = w1p[2 * q], u1 = w1p[2 * q + 1];
            hp = fmaf(zq.x, __uint_as_float(u0 << 16), hp);
            hp = fmaf(zq.y, __uint_as_float(u0 & 0xFFFF0000u), hp);
            hp = fmaf(zq.z, __uint_as_float(u1 << 16), hp);
            hp = fmaf(zq.w, __uint_as_float(u1 & 0xFFFF0000u), hp);
        }
        hp += __shfl_xor(hp, 32);
        logacc += tanh_fast(hp + b1r) * w2r;       // lane-sum over wave = 2x logit
    }
#pragma unroll
    for (int off = 1; off < 64; off <<= 1) logacc += __shfl_xor(logacc, off);
    if (lane == 0) atomicAdd(&wsum[(blockIdx.x & (WSLOTS - 1)) * PP + p], logacc * 0.5f);
}

// ---------------------------------------------------------------- beta = softmax(mean logits)
__global__ void beta_kernel(const float* __restrict__ wsum, float* __restrict__ beta) {
    if (threadIdx.x == 0) {
        float m[PP] = {0.f, 0.f, 0.f};
        for (int i = 0; i < WSLOTS; ++i)
            for (int p = 0; p < PP; ++p) m[p] += wsum[i * PP + p];
        float mx = -1e30f;
        for (int p = 0; p < PP; ++p) { m[p] *= (1.0f / NN); mx = fmaxf(mx, m[p]); }
        float e[PP], s = 0.f;
        for (int p = 0; p < PP; ++p) { e[p] = expf(m[p] - mx); s += e[p]; }
        for (int p = 0; p < PP; ++p) beta[p] = e[p] / s;
    }
}

// ---------------------------------------------------------------- out = sum_p beta[p] * z[:,p,:]
__global__ void out_kernel(const float* __restrict__ zbuf, const float* __restrict__ beta,
                           float* __restrict__ out) {
    int t = blockIdx.x * 256 + threadIdx.x;
    if (t >= NN * (OUT_F / 4)) return;
    int n = t >> 4;
    int q = t & 15;
    float b0 = beta[0], b1 = beta[1], b2 = beta[2];
    const float4 v0 = ((const float4*)(zbuf + ((size_t)n * PP + 0) * OUT_F))[q];
    const float4 v1 = ((const float4*)(zbuf + ((size_t)n * PP + 1) * OUT_F))[q];
    const float4 v2 = ((const float4*)(zbuf + ((size_t)n * PP + 2) * OUT_F))[q];
    float4 r;
    r.x = b0 * v0.x + b1 * v1.x + b2 * v2.x;
    r.y = b0 * v0.y + b1 * v1.y + b2 * v2.y;
    r.z = b0 * v0.z + b1 * v1.z + b2 * v2.z;
    r.w = b0 * v0.w + b1 * v1.w + b2 * v2.w;
    ((float4*)out)[t] = r;
}

extern "C" void kernel_launch(void* const* d_in, const int* in_sizes, int n_in,
                              void* d_out, int out_size, void* d_ws, size_t ws_size,
                              hipStream_t stream) {
    const float* h     = (const float*)d_in[0];
    const float* gc_w  = (const float*)d_in[1];
    const float* gc_b  = (const float*)d_in[2];
    const float* sa_w1 = (const float*)d_in[3];
    const float* sa_b1 = (const float*)d_in[4];
    const float* sa_w2 = (const float*)d_in[5];
    const int* esrc    = (const int*)d_in[6];
    const int* edst    = (const int*)d_in[7];

    float* out  = (float*)d_out;
    float* zbuf = out + (size_t)NN * OUT_F;              // z region of d_out: [N][P][64]
    unsigned short* tproj = (unsigned short*)out;        // single bf16 proj table: out[0:12.8M)

    char* ws = (char*)d_ws;                              // peak ws use ~37.3 MB (43.5 MB proven, round 6)
    const size_t OFF_GBD  = 0;                           // gbuf_d: 294*19456*4 = 22,880,256
    const size_t OFF_GBS  = 22900000;                    // gbuf_s u16: 12,644,352 (freed after src_hist)
    const size_t OFF_DEG  = 35600000;                    // deg8 [3][NN]: 300,000
    const size_t OFF_FOFF = 36000000;                    // 37,632
    const size_t OFF_FCNT = 36050000;                    // 37,632
    const size_t OFF_GCD  = 36100000;
    const size_t OFF_GCS  = 36110000;
    const size_t OFF_WSUM = 36120000;
    const size_t OFF_BETA = 36130000;

    unsigned* gbuf_d       = (unsigned*)(ws + OFF_GBD);
    unsigned short* gbuf_s = (unsigned short*)(ws + OFF_GBS);
    unsigned char* deg8    = (unsigned char*)(ws + OFF_DEG);
    unsigned* foff         = (unsigned*)(ws + OFF_FOFF);
    unsigned* fcnt         = (unsigned*)(ws + OFF_FCNT);
    unsigned* gcur_d       = (unsigned*)(ws + OFF_GCD);
    unsigned* gcur_s       = (unsigned*)(ws + OFF_GCS);
    float* wsum            = (float*)(ws + OFF_WSUM);
    float* beta            = (float*)(ws + OFF_BETA);

    hipMemsetAsync(gcur_d, 0, NCB * sizeof(unsigned), stream);
    hipMemsetAsync(gcur_s, 0, NCB * sizeof(unsigned), stream);
    hipMemsetAsync(wsum, 0, WSLOTS * PP * sizeof(float), stream);

    scatter_sortd<<<dim3(NSX, PP), 256, 0, stream>>>(esrc, edst, gcur_d, gbuf_d);
    scatter_sorts<<<dim3(NSX, PP), 256, 0, stream>>>(esrc, gcur_s, gbuf_s);
    src_hist<<<NCB, 256, 0, stream>>>(gcur_s, gbuf_s, deg8);              // consumes gbuf_s
    proj_kernel<<<NN / 32, 256, 0, stream>>>(h, gc_w, tproj);             // single unscaled table
    fine_split<<<NCB, 256, 0, stream>>>(gcur_d, gbuf_d, deg8, foff, fcnt);
    gather3d<<<NFB, 256, 0, stream>>>(foff, fcnt, gbuf_d, tproj,
                                      gc_b, sa_w1, sa_b1, sa_w2, zbuf, wsum);
    beta_kernel<<<1, 64, 0, stream>>>(wsum, beta);
    out_kernel<<<(NN * (OUT_F / 4) + 255) / 256, 256, 0, stream>>>(zbuf, beta, out);
}

// Round 27
// 398.965 us; speedup vs baseline: 1.1017x; 1.0403x over previous
//
#include <hip/hip_runtime.h>

#define NN 100000
#define IN_F 128
#define OUT_F 64
#define PP 3
#define EE 1600000
#define TOT (PP * EE)                // 4.8M edges
#define HID 32
#define SEG_N (PP * NN)              // 300000
#define NC1024 98                    // coarse blocks of 1024 nodes
#define NCB (NC1024 * PP)            // 294 coarse bins
#define CAPC 19456                   // coarse dst-bin capacity (mult of 16)
#define CAPS 21504                   // coarse src-bin capacity u16 (mult of 32)
#define CHUNK 8192                   // edges per scatter block
#define NSX ((EE + CHUNK - 1) / CHUNK)      // 196 scatter blocks per metapath
#define LCAP 64                      // per-node edge list capacity
#define NFB (NCB * 32)               // 9408 fine bins
#define WSLOTS 256

__device__ __forceinline__ unsigned short f2bf(float f) {
    unsigned u = __float_as_uint(f);
    u += 0x7FFFu + ((u >> 16) & 1u);           // round to nearest even
    return (unsigned short)(u >> 16);
}
__device__ __forceinline__ float bf2f(unsigned short b) {
    return __uint_as_float((unsigned)b << 16);
}
__device__ __forceinline__ float tanh_fast(float x) {
    float ax = fabsf(x);
    float e = __expf(-2.f * ax);
    float t = (1.f - e) / (1.f + e);
    return copysignf(t, x);
}

// ---------------------------------------------------------------- two-key coarse multisplit, p = blockIdx.y
// Per-wave LDS histograms, block bulk run reservation, dense placement. (Round-14 proven: 142us.)
__global__ void scatter_coarse(const int* __restrict__ src, const int* __restrict__ dst,
                               unsigned* __restrict__ gcur_d, unsigned* __restrict__ gcur_s,
                               unsigned* __restrict__ gbuf_d, unsigned short* __restrict__ gbuf_s) {
    __shared__ unsigned cnt_d[4][NC1024], cnt_s[4][NC1024];
    int tid = threadIdx.x;
    int wv = tid >> 6;
    int p = blockIdx.y;
    for (int i = tid; i < 4 * NC1024; i += 256) { cnt_d[i / NC1024][i % NC1024] = 0u; cnt_s[i / NC1024][i % NC1024] = 0u; }
    __syncthreads();
    int e0 = blockIdx.x * CHUNK;
    const int* sp = src + (size_t)p * EE;
    const int* dp = dst + (size_t)p * EE;
    // pass 1: per-wave LDS histograms
    for (int i = 0; i < CHUNK / 256; ++i) {
        int e = e0 + i * 256 + tid;
        if (e < EE) {
            atomicAdd(&cnt_d[wv][dp[e] >> 10], 1u);
            atomicAdd(&cnt_s[wv][sp[e] >> 10], 1u);
        }
    }
    __syncthreads();
    // bulk-reserve; cnt_[wv][bin] becomes each wave's absolute write cursor
    for (int i = tid; i < NC1024; i += 256) {
        unsigned c0 = cnt_d[0][i], c1 = cnt_d[1][i], c2 = cnt_d[2][i], c3 = cnt_d[3][i];
        unsigned tt = c0 + c1 + c2 + c3;
        unsigned base = tt ? atomicAdd(&gcur_d[i * PP + p], tt) : 0u;
        cnt_d[0][i] = base; cnt_d[1][i] = base + c0;
        cnt_d[2][i] = base + c0 + c1; cnt_d[3][i] = base + c0 + c1 + c2;
        c0 = cnt_s[0][i]; c1 = cnt_s[1][i]; c2 = cnt_s[2][i]; c3 = cnt_s[3][i];
        tt = c0 + c1 + c2 + c3;
        base = tt ? atomicAdd(&gcur_s[i * PP + p], tt) : 0u;
        cnt_s[0][i] = base; cnt_s[1][i] = base + c0;
        cnt_s[2][i] = base + c0 + c1; cnt_s[3][i] = base + c0 + c1 + c2;
    }
    __syncthreads();
    // pass 2: dense placement (per-wave LDS cursor atomics)
    for (int i = 0; i < CHUNK / 256; ++i) {
        int e = e0 + i * 256 + tid;
        if (e < EE) {
            int s = sp[e], d = dp[e];
            unsigned pd = atomicAdd(&cnt_d[wv][d >> 10], 1u);
            unsigned ps = atomicAdd(&cnt_s[wv][s >> 10], 1u);
            if (pd < CAPC) gbuf_d[(size_t)((d >> 10) * PP + p) * CAPC + pd] = (unsigned)s | ((unsigned)(d & 1023) << 17);
            if (ps < CAPS) gbuf_s[(size_t)((s >> 10) * PP + p) * CAPS + ps] = (unsigned short)(s & 1023);
        }
    }
}

// ---------------------------------------------------------------- per-coarse-src-bin LDS histogram -> nsrc (f32)
__global__ void src_hist(const unsigned* __restrict__ gcur_s, const unsigned short* __restrict__ gbuf_s,
                         float* __restrict__ nsrc) {
    __shared__ unsigned hist[4][1024];   // 16 KB
    int tid = threadIdx.x;
    int wv = tid >> 6;
    for (int i = tid; i < 4 * 1024; i += 256) hist[i >> 10][i & 1023] = 0u;
    __syncthreads();
    int c = blockIdx.x;
    int blk = c / PP, p = c - blk * PP;
    unsigned cnt = gcur_s[c]; if (cnt > CAPS) cnt = CAPS;
    const unsigned short* gb = gbuf_s + (size_t)c * CAPS;
    for (unsigned j = tid; j < cnt; j += 256) atomicAdd(&hist[wv][gb[j]], 1u);
    __syncthreads();
    for (int i = tid; i < 1024; i += 256) {
        int n = blk * 1024 + i;
        unsigned hv = hist[0][i] + hist[1][i] + hist[2][i] + hist[3][i];
        if (n < NN) nsrc[p * NN + n] = rsqrtf(fmaxf((float)hv, 1.f));
    }
}

// ---------------------------------------------------------------- proj_fused: projp_p = (h @ gc_w) * nsrc_p, bf16
__global__ void __launch_bounds__(256) proj_fused(const float* __restrict__ h,
                                                  const float* __restrict__ gc_w,
                                                  const float* __restrict__ nsrc,
                                                  unsigned short* __restrict__ t0,
                                                  unsigned short* __restrict__ t1,
                                                  unsigned short* __restrict__ t2) {
    __shared__ float w_lds[IN_F * OUT_F];   // 32 KB
    __shared__ float h_lds[32 * IN_F];      // 16 KB
    int tid = threadIdx.x;
    for (int i = tid; i < IN_F * OUT_F / 4; i += 256)
        ((float4*)w_lds)[i] = ((const float4*)gc_w)[i];
    size_t r0 = (size_t)blockIdx.x * 32;
    for (int i = tid; i < 32 * IN_F / 4; i += 256)
        ((float4*)h_lds)[i] = ((const float4*)(h + r0 * IN_F))[i];
    __syncthreads();
    int wave = tid >> 6, lane = tid & 63;
    float acc[8] = {0.f, 0.f, 0.f, 0.f, 0.f, 0.f, 0.f, 0.f};
    for (int k = 0; k < IN_F; k += 4) {
        float w0 = w_lds[k * OUT_F + lane];
        float w1 = w_lds[(k + 1) * OUT_F + lane];
        float w2 = w_lds[(k + 2) * OUT_F + lane];
        float w3 = w_lds[(k + 3) * OUT_F + lane];
#pragma unroll
        for (int r = 0; r < 8; ++r) {
            float4 hv = *(const float4*)&h_lds[(wave * 8 + r) * IN_F + k];
            acc[r] = fmaf(hv.x, w0, fmaf(hv.y, w1, fmaf(hv.z, w2, fmaf(hv.w, w3, acc[r]))));
        }
    }
#pragma unroll
    for (int r = 0; r < 8; ++r) {
        size_t n = r0 + wave * 8 + r;
        float a = acc[r];
        t0[n * OUT_F + lane] = f2bf(a * nsrc[n]);
        t1[n * OUT_F + lane] = f2bf(a * nsrc[NN + n]);
        t2[n * OUT_F + lane] = f2bf(a * nsrc[2 * NN + n]);
    }
}

// ---------------------------------------------------------------- fine split IN PLACE: stage coarse bin in LDS,
// histogram 32 sub-bins, re-permute back into the same global slice. Payload out: s (17b) | node (5b @17).
__global__ void fine_split(const unsigned* __restrict__ gcur_d, unsigned* __restrict__ gbuf_d,
                           unsigned* __restrict__ foff, unsigned* __restrict__ fcnt) {
    __shared__ unsigned stage[CAPC];     // 76 KB
    __shared__ unsigned hist[4][32], pre[32], cur[4][32];
    int c = blockIdx.x;
    int tid = threadIdx.x;
    int wv = tid >> 6;
    if (tid < 32) { hist[0][tid] = 0u; hist[1][tid] = 0u; hist[2][tid] = 0u; hist[3][tid] = 0u; }
    __syncthreads();
    unsigned cnt = gcur_d[c]; if (cnt > CAPC) cnt = CAPC;
    unsigned* gb = gbuf_d + (size_t)c * CAPC;
    for (unsigned j = tid; j < cnt; j += 256) {
        unsigned v = gb[j];
        stage[j] = v;
        atomicAdd(&hist[wv][v >> 22], 1u);        // sub = (d&1023)>>5
    }
    __syncthreads();
    if (tid == 0) {
        unsigned a = 0;
        for (int i = 0; i < 32; ++i) {
            pre[i] = a;
            a += hist[0][i] + hist[1][i] + hist[2][i] + hist[3][i];
        }
    }
    __syncthreads();
    if (tid < 32) {
        unsigned a = pre[tid];
        cur[0][tid] = a; a += hist[0][tid];
        cur[1][tid] = a; a += hist[1][tid];
        cur[2][tid] = a; a += hist[2][tid];
        cur[3][tid] = a; a += hist[3][tid];
        foff[c * 32 + tid] = (unsigned)c * CAPC + pre[tid];
        fcnt[c * 32 + tid] = a - pre[tid];
    }
    __syncthreads();
    for (unsigned j = tid; j < cnt; j += 256) {
        unsigned v = stage[j];
        unsigned pos = atomicAdd(&cur[wv][v >> 22], 1u);
        gb[pos] = v & 0x3FFFFFu;                  // strip sub, keep s | node<<17
    }
}

// ---------------------------------------------------------------- fine gather: weight-free inner loop
// (prescaled tables): per edge = readlane + load + shift + add.
__global__ void __launch_bounds__(256, 8)
gather3d(const unsigned* __restrict__ foff, const unsigned* __restrict__ fcnt,
         const unsigned* __restrict__ gbuf_f,
         const unsigned short* __restrict__ t0, const unsigned short* __restrict__ t1,
         const unsigned short* __restrict__ t2,
         const float* __restrict__ gc_b, const float* __restrict__ sa_w1,
         const float* __restrict__ sa_b1, const float* __restrict__ sa_w2,
         float* __restrict__ zbuf, float* __restrict__ wsum) {
    __shared__ unsigned lists[32 * LCAP];   // 8 KB
    __shared__ unsigned lcnt[32];
    __shared__ float zsh[4][OUT_F];
    int tid = threadIdx.x;
    int lane = tid & 63, wave = tid >> 6;
    int j = lane & 31, half = lane >> 5;
    unsigned w1p[16];                       // packed bf16 pairs of sa_w1
#pragma unroll
    for (int q = 0; q < 16; ++q) {
        float a = sa_w1[(half * 32 + 2 * q) * HID + j];
        float b = sa_w1[(half * 32 + 2 * q + 1) * HID + j];
        w1p[q] = (unsigned)f2bf(a) | ((unsigned)f2bf(b) << 16);
    }
    float b1r = sa_b1[j];
    float w2r = sa_w2[j];
    float bsr = gc_b[lane];
    if (tid < 32) lcnt[tid] = 0u;
    __syncthreads();

    int f = blockIdx.x;                  // fine bin: c*32 + sub
    int c = f >> 5, sub = f & 31;
    int blk = c / PP, p = c - blk * PP;
    const unsigned short* tp = (p == 0) ? t0 : (p == 1) ? t1 : t2;
    unsigned base = foff[f];
    unsigned cnt = fcnt[f];
    for (unsigned i = tid; i < cnt; i += 256) {
        unsigned v = gbuf_f[base + i];
        unsigned node = (v >> 17) & 31;
        unsigned sl = atomicAdd(&lcnt[node], 1u);
        if (sl < LCAP) lists[node * LCAP + sl] = v;
    }
    __syncthreads();

    int nbase = blk * 1024 + sub * 32;
    float logacc = 0.f;
    for (int k = 0; k < 8; ++k) {            // 8 nodes per wave
        int node = wave * 8 + k;
        int n = nbase + node;
        if (n >= NN) continue;
        unsigned ind = lcnt[node];
        unsigned c2 = ind < LCAP ? ind : LCAP;
        unsigned pl = lists[node * LCAP + lane];
        float acc = 0.f;
        unsigned i = 0;
        for (; i + 4 <= c2; i += 4) {
            unsigned a0 = (unsigned)__builtin_amdgcn_readlane((int)pl, (int)i);
            unsigned a1 = (unsigned)__builtin_amdgcn_readlane((int)pl, (int)i + 1);
            unsigned a2 = (unsigned)__builtin_amdgcn_readlane((int)pl, (int)i + 2);
            unsigned a3 = (unsigned)__builtin_amdgcn_readlane((int)pl, (int)i + 3);
            float p0 = bf2f(tp[(size_t)(a0 & 0x1FFFFu) * OUT_F + lane]);
            float p1 = bf2f(tp[(size_t)(a1 & 0x1FFFFu) * OUT_F + lane]);
            float p2 = bf2f(tp[(size_t)(a2 & 0x1FFFFu) * OUT_F + lane]);
            float p3 = bf2f(tp[(size_t)(a3 & 0x1FFFFu) * OUT_F + lane]);
            acc += (p0 + p1) + (p2 + p3);
        }
        for (; i < c2; ++i) {
            unsigned a0 = (unsigned)__builtin_amdgcn_readlane((int)pl, (int)i);
            acc += bf2f(tp[(size_t)(a0 & 0x1FFFFu) * OUT_F + lane]);
        }
        float ndv = rsqrtf(fmaxf((float)ind, 1.f));
        float zv = fmaxf(fmaf(acc, ndv, bsr), 0.f);
        zbuf[((size_t)n * PP + p) * OUT_F + lane] = zv;
        zsh[wave][lane] = zv;
        float hp = 0.f;
        const float4* zrow = (const float4*)&zsh[wave][half * 32];
#pragma unroll
        for (int q = 0; q < 8; ++q) {
            float4 zq = zrow[q];
            unsigned u0 = w1p[2 * q], u1 = w1p[2 * q + 1];
            hp = fmaf(zq.x, __uint_as_float(u0 << 16), hp);
            hp = fmaf(zq.y, __uint_as_float(u0 & 0xFFFF0000u), hp);
            hp = fmaf(zq.z, __uint_as_float(u1 << 16), hp);
            hp = fmaf(zq.w, __uint_as_float(u1 & 0xFFFF0000u), hp);
        }
        hp += __shfl_xor(hp, 32);
        logacc += tanh_fast(hp + b1r) * w2r;       // lane-sum over wave = 2x logit
    }
#pragma unroll
    for (int off = 1; off < 64; off <<= 1) logacc += __shfl_xor(logacc, off);
    if (lane == 0) atomicAdd(&wsum[(blockIdx.x & (WSLOTS - 1)) * PP + p], logacc * 0.5f);
}

// ---------------------------------------------------------------- beta = softmax(mean logits)
__global__ void beta_kernel(const float* __restrict__ wsum, float* __restrict__ beta) {
    if (threadIdx.x == 0) {
        float m[PP] = {0.f, 0.f, 0.f};
        for (int i = 0; i < WSLOTS; ++i)
            for (int p = 0; p < PP; ++p) m[p] += wsum[i * PP + p];
        float mx = -1e30f;
        for (int p = 0; p < PP; ++p) { m[p] *= (1.0f / NN); mx = fmaxf(mx, m[p]); }
        float e[PP], s = 0.f;
        for (int p = 0; p < PP; ++p) { e[p] = expf(m[p] - mx); s += e[p]; }
        for (int p = 0; p < PP; ++p) beta[p] = e[p] / s;
    }
}

// ---------------------------------------------------------------- out = sum_p beta[p] * z[:,p,:]
__global__ void out_kernel(const float* __restrict__ zbuf, const float* __restrict__ beta,
                           float* __restrict__ out) {
    int t = blockIdx.x * 256 + threadIdx.x;
    if (t >= NN * (OUT_F / 4)) return;
    int n = t >> 4;
    int q = t & 15;
    float b0 = beta[0], b1 = beta[1], b2 = beta[2];
    const float4 v0 = ((const float4*)(zbuf + ((size_t)n * PP + 0) * OUT_F))[q];
    const float4 v1 = ((const float4*)(zbuf + ((size_t)n * PP + 1) * OUT_F))[q];
    const float4 v2 = ((const float4*)(zbuf + ((size_t)n * PP + 2) * OUT_F))[q];
    float4 r;
    r.x = b0 * v0.x + b1 * v1.x + b2 * v2.x;
    r.y = b0 * v0.y + b1 * v1.y + b2 * v2.y;
    r.z = b0 * v0.z + b1 * v1.z + b2 * v2.z;
    r.w = b0 * v0.w + b1 * v1.w + b2 * v2.w;
    ((float4*)out)[t] = r;
}

extern "C" void kernel_launch(void* const* d_in, const int* in_sizes, int n_in,
                              void* d_out, int out_size, void* d_ws, size_t ws_size,
                              hipStream_t stream) {
    const float* h     = (const float*)d_in[0];
    const float* gc_w  = (const float*)d_in[1];
    const float* gc_b  = (const float*)d_in[2];
    const float* sa_w1 = (const float*)d_in[3];
    const float* sa_b1 = (const float*)d_in[4];
    const float* sa_w2 = (const float*)d_in[5];
    const int* esrc    = (const int*)d_in[6];
    const int* edst    = (const int*)d_in[7];

    float* out  = (float*)d_out;
    float* zbuf = out + (size_t)NN * OUT_F;              // z region of d_out: [N][P][64]
    unsigned short* t0 = (unsigned short*)out;           // projp0: out[0:12.8M)
    unsigned short* t1 = t0 + (size_t)NN * OUT_F;        // projp1: out[12.8:25.6M)

    char* ws = (char*)d_ws;                              // peak ws use ~37.3 MB (41.4 MB proven)
    const size_t OFF_GBD  = 0;                           // gbuf_d: 294*19456*4 = 22,880,256
    const size_t OFF_GBS  = 22900000;                    // gbuf_s u16 (freed after src_hist)
    const size_t OFF_T2   = 22900000;                    // projp2 (12.8M) — overlays gbuf_s after src_hist
    const size_t OFF_NSRC = 35800000;                    // nsrc f32 [3][NN]
    const size_t OFF_FOFF = 37100000;
    const size_t OFF_FCNT = 37150000;
    const size_t OFF_GCD  = 37200000;
    const size_t OFF_GCS  = 37210000;
    const size_t OFF_WSUM = 37220000;
    const size_t OFF_BETA = 37230000;

    unsigned* gbuf_d       = (unsigned*)(ws + OFF_GBD);
    unsigned short* gbuf_s = (unsigned short*)(ws + OFF_GBS);
    unsigned short* t2     = (unsigned short*)(ws + OFF_T2);
    float* nsrc            = (float*)(ws + OFF_NSRC);
    unsigned* foff         = (unsigned*)(ws + OFF_FOFF);
    unsigned* fcnt         = (unsigned*)(ws + OFF_FCNT);
    unsigned* gcur_d       = (unsigned*)(ws + OFF_GCD);
    unsigned* gcur_s       = (unsigned*)(ws + OFF_GCS);
    float* wsum            = (float*)(ws + OFF_WSUM);
    float* beta            = (float*)(ws + OFF_BETA);

    hipMemsetAsync(gcur_d, 0, NCB * sizeof(unsigned), stream);
    hipMemsetAsync(gcur_s, 0, NCB * sizeof(unsigned), stream);
    hipMemsetAsync(wsum, 0, WSLOTS * PP * sizeof(float), stream);

    scatter_coarse<<<dim3(NSX, PP), 256, 0, stream>>>(esrc, edst, gcur_d, gcur_s, gbuf_d, gbuf_s);
    src_hist<<<NCB, 256, 0, stream>>>(gcur_s, gbuf_s, nsrc);              // consumes gbuf_s
    proj_fused<<<NN / 32, 256, 0, stream>>>(h, gc_w, nsrc, t0, t1, t2);   // t2 overlays freed gbuf_s
    fine_split<<<NCB, 256, 0, stream>>>(gcur_d, gbuf_d, foff, fcnt);      // in-place permute
    gather3d<<<NFB, 256, 0, stream>>>(foff, fcnt, gbuf_d, t0, t1, t2,
                                      gc_b, sa_w1, sa_b1, sa_w2, zbuf, wsum);
    beta_kernel<<<1, 64, 0, stream>>>(wsum, beta);
    out_kernel<<<(NN * (OUT_F / 4) + 255) / 256, 256, 0, stream>>>(zbuf, beta, out);
}